// Round 5
// baseline (188.495 us; speedup 1.0000x reference)
//
#include <hip/hip_runtime.h>

typedef _Float16 f16x8 __attribute__((ext_vector_type(8)));
typedef _Float16 f16x4 __attribute__((ext_vector_type(4)));
typedef float    f32x4 __attribute__((ext_vector_type(4)));

#define MFMA16(A, B, C) __builtin_amdgcn_mfma_f32_16x16x32_f16((A), (B), (C), 0, 0, 0)

constexpr int Bsz = 4096, Ssz = 200, INsz = 8, Hsz = 128, OUTsz = 8, Psz = 50;
constexpr int ROWS = 8;    // REAL batch rows per block (MFMA tile holds 8 real + 8 dup)
// d_ws layout (floats): G[128*128] @0 ; Go[8*128] @16384 ; d[128] @17408 ; co[8] @17536
constexpr int WS_G = 0, WS_GO = 16384, WS_D = 17408, WS_CO = 17536;

// ---------------- prologue: fold weight products ----------------
// G = W1@W2 (128x128), Go = Wout@W2 (8x128), d = W1@b2 (128), co = Wout@b2 (8)
__global__ void precomp_kernel(const float* __restrict__ W1, const float* __restrict__ W2,
                               const float* __restrict__ b2, const float* __restrict__ Wout,
                               float* __restrict__ ws) {
  int tid = (int)blockIdx.x * 256 + (int)threadIdx.x;
  if (tid < 16384) {                       // G[j][k]
    int j = tid >> 7, k = tid & 127;
    float acc = 0.f;
    #pragma unroll 8
    for (int m = 0; m < 128; ++m) acc = fmaf(W1[j*128 + m], W2[m*128 + k], acc);
    ws[WS_G + tid] = acc;
  } else if (tid < 16384 + 1024) {         // Go[o][k]
    int t = tid - 16384; int o = t >> 7, k = t & 127;
    float acc = 0.f;
    #pragma unroll 8
    for (int m = 0; m < 128; ++m) acc = fmaf(Wout[o*128 + m], W2[m*128 + k], acc);
    ws[WS_GO + t] = acc;
  } else if (tid < 16384 + 1024 + 128) {   // d[j] = sum_m b2[m]*W1[j][m]
    int j = tid - 17408;
    float acc = 0.f;
    for (int m = 0; m < 128; ++m) acc = fmaf(b2[m], W1[j*128 + m], acc);
    ws[WS_D + j] = acc;
  } else if (tid < 16384 + 1024 + 128 + 8) { // co[o] = sum_m b2[m]*Wout[o][m]
    int o = tid - 17536;
    float acc = 0.f;
    for (int m = 0; m < 128; ++m) acc = fmaf(b2[m], Wout[o*128 + m], acc);
    ws[WS_CO + o] = acc;
  }
}

// split fp32 x8 into fp16 hi + fp16 residual (register-resident weight frags)
#define SPLIT8(PTR, HI, LO) do { \
    const f32x4 va_ = *(const f32x4*)(PTR); \
    const f32x4 vb_ = *(const f32x4*)((PTR) + 4); \
    _Pragma("unroll") \
    for (int j_ = 0; j_ < 4; ++j_) { \
      _Float16 h0_ = (_Float16)va_[j_]; \
      (HI)[j_]     = h0_; \
      (LO)[j_]     = (_Float16)(va_[j_] - (float)h0_); \
      _Float16 h1_ = (_Float16)vb_[j_]; \
      (HI)[j_ + 4] = h1_; \
      (LO)[j_ + 4] = (_Float16)(vb_[j_] - (float)h1_); \
    } \
  } while (0)

// single-tile matmul stage: O = frag(B) @ A^T + bias ; packed conflict-free LDS
// reads; 3-product hi/lo split (uh*Wh + uh*Wl + ul*Wh), 3 chains of depth 4.
#define STG(BH, BL, AH, AL, BI, O) do { \
    f32x4 c_ = (BI); \
    f32x4 e_ = {0.f,0.f,0.f,0.f}, f_ = {0.f,0.f,0.f,0.f}; \
    _Pragma("unroll") \
    for (int ks_ = 0; ks_ < 4; ++ks_) { \
      const f16x8 uh_ = *(const f16x8*)(&(BH)[(ks_*64 + l)*8]); \
      const f16x8 ul_ = *(const f16x8*)(&(BL)[(ks_*64 + l)*8]); \
      c_ = MFMA16((AH)[ks_], uh_, c_); \
      e_ = MFMA16((AL)[ks_], uh_, e_); \
      f_ = MFMA16((AH)[ks_], ul_, f_); \
    } \
    (O) = c_ + e_ + f_; \
  } while (0)

// write this lane's 4 channels (chans ch0+4g..+3 of tile-row r) into the
// packed hi/lo frag arrays at precomputed slot wb0 (one ds_write_b64 each)
#define WPK(DH, DL, V) do { \
    f16x4 wh_, wl_; \
    _Pragma("unroll") \
    for (int q_ = 0; q_ < 4; ++q_) { \
      _Float16 hh_ = (_Float16)(V)[q_]; \
      wh_[q_] = hh_; wl_[q_] = (_Float16)((V)[q_] - (float)hh_); \
    } \
    *(f16x4*)(&(DH)[wb0]) = wh_; \
    *(f16x4*)(&(DL)[wb0]) = wl_; \
  } while (0)

__device__ inline f32x4 tanh4(f32x4 z) {
  f32x4 o;
  #pragma unroll
  for (int q = 0; q < 4; ++q) {
    float zz = fminf(fmaxf(z[q], -15.f), 15.f);
    float e  = __builtin_amdgcn_exp2f(2.8853900817779268f * zz); // e^(2x)
    o[q] = (e - 1.f) * __builtin_amdgcn_rcpf(e + 1.f);
  }
  return o;
}

__global__ __launch_bounds__(512, 4) void node_rk4_kernel(
    const float* __restrict__ x,    const float* __restrict__ Win,
    const float* __restrict__ binp, const float* __restrict__ W1,
    const float* __restrict__ b1,   const float* __restrict__ Wout,
    const float* __restrict__ bout, const float* __restrict__ ws,
    float* __restrict__ out)
{
  // packed frag buffers: slot (ks,lane) holds 8 halves = chans [32ks+8*(l>>4)..+8) of row l&15
  __shared__ _Float16 bufA_hi[2048], bufA_lo[2048], bufB_hi[2048], bufB_lo[2048];

  const int tid = (int)threadIdx.x;
  const int w   = tid >> 6;   // wave 0..7, owns channels [16w, 16w+16)
  const int l   = tid & 63;
  const int g   = l >> 4;
  const int r   = l & 15;     // MFMA tile row (0..15); rows 8..15 duplicate 0..7
  const int rr  = r & 7;      // real batch row within block
  const int rowbase = (int)blockIdx.x * ROWS;
  const int ch0 = w * 16;
  // packed write slot for chans ch0+4g+q of tile-row r
  const int wb0 = ((w >> 1)*512 + (2*(w & 1) + (g >> 1))*128 + r*8) + 4*(g & 1);

  // ---------- persistent weight fragments ----------
  f16x8 Gh[4], Gl[4];              // G rows [ch0+r][*] for this wave's 16 chans
  #pragma unroll
  for (int ks = 0; ks < 4; ++ks)
    SPLIT8(ws + WS_G + (size_t)(ch0 + r)*Hsz + 32*ks + 8*g, Gh[ks], Gl[ks]);

  f16x8 goh[4], gol[4];            // Go rows (8 real, padded to 16) — used by wave 0
  #pragma unroll
  for (int ks = 0; ks < 4; ++ks) {
    if (r < OUTsz) SPLIT8(ws + WS_GO + (size_t)r*Hsz + 32*ks + 8*g, goh[ks], gol[ks]);
    else {
      #pragma unroll
      for (int j = 0; j < 8; ++j) { goh[ks][j] = (_Float16)0.f; gol[ks][j] = (_Float16)0.f; }
    }
  }

  // bias vectors (acc reg q <-> chan ch0+4g+q)
  const f32x4 dv  = *(const f32x4*)(ws + WS_D + ch0 + 4*g);
  const f32x4 dv6 = 6.f * dv;
  f32x4 cov6, boutv;
  if (g < 2) { cov6 = 6.f * *(const f32x4*)(ws + WS_CO + 4*g);
               boutv = *(const f32x4*)(bout + 4*g); }
  else { cov6 = f32x4{0.f,0.f,0.f,0.f}; boutv = f32x4{0.f,0.f,0.f,0.f}; }

  // ---------- y0 = x[:, S-1, :] @ Win^T + bin (this lane's 4 chans) ----------
  const float* xr = x + ((size_t)(rowbase + rr)*Ssz + (Ssz - 1))*INsz;
  const f32x4 xa = *(const f32x4*)xr;
  const f32x4 xb = *(const f32x4*)(xr + 4);
  f32x4 yv;
  {
    const f32x4 binv = *(const f32x4*)(binp + ch0 + 4*g);
    #pragma unroll
    for (int q = 0; q < 4; ++q) {
      const float* wrp = Win + (size_t)(ch0 + 4*g + q)*INsz;
      const f32x4 wa = *(const f32x4*)wrp;
      const f32x4 wb = *(const f32x4*)(wrp + 4);
      float acc = binv[q];
      #pragma unroll
      for (int i = 0; i < 4; ++i) acc += xa[i]*wa[i] + xb[i]*wb[i];
      yv[q] = acc;
    }
  }

  WPK(bufA_hi, bufA_lo, yv);   // stage y0 frags
  __syncthreads();

  // ---------- init: z = y0@W1^T + b1 (all waves), o = y0@Wout^T (wave 0) ----------
  f32x4 z, o;
  {
    f16x8 a1h[4], a1l[4];           // transient W1 frags
    #pragma unroll
    for (int ks = 0; ks < 4; ++ks)
      SPLIT8(W1 + (size_t)(ch0 + r)*Hsz + 32*ks + 8*g, a1h[ks], a1l[ks]);
    const f32x4 b1v = *(const f32x4*)(b1 + ch0 + 4*g);
    STG(bufA_hi, bufA_lo, a1h, a1l, b1v, z);

    if (w == 0) {
      f16x8 woh[4], wol[4];         // transient Wout frags (padded)
      #pragma unroll
      for (int ks = 0; ks < 4; ++ks) {
        if (r < OUTsz) SPLIT8(Wout + (size_t)r*Hsz + 32*ks + 8*g, woh[ks], wol[ks]);
        else {
          #pragma unroll
          for (int j = 0; j < 8; ++j) { woh[ks][j] = (_Float16)0.f; wol[ks][j] = (_Float16)0.f; }
        }
      }
      const f32x4 zero = {0.f,0.f,0.f,0.f};
      STG(bufA_hi, bufA_lo, woh, wol, zero, o);
    } else {
      o = f32x4{0.f,0.f,0.f,0.f};
    }
  }
  __syncthreads();   // bufA readers done before loop's s1 overwrites it

  // ---------- RK4 in z-space: 4 matmuls + 4 barriers per step ----------
  f32x4 Ta, m, t;
  #pragma unroll 1
  for (int p = 0; p < Psz; ++p) {
    if (w == 0 && g < 2 && r < ROWS) {   // out_p = o + bout (real rows only)
      float* dst = out + ((size_t)(rowbase + r)*Psz + p)*OUTsz + 4*g;
      *(f32x4*)dst = o + boutv;
    }
    if (p == Psz - 1) break;

    // s1: t1 = tanh(z) ; Ta = t1 ; -> bufA
    t = tanh4(z);
    Ta = t;
    WPK(bufA_hi, bufA_lo, t);
    __syncthreads();

    // s2: m = t1@G^T + d ; t2 = tanh(z + 0.5m) -> bufB
    STG(bufA_hi, bufA_lo, Gh, Gl, dv, m);
    t = tanh4(z + 0.5f*m);
    Ta += 2.f*t;
    WPK(bufB_hi, bufB_lo, t);
    __syncthreads();

    // s3: m = t2@G^T + d ; t3 = tanh(z + 0.5m) -> bufA
    STG(bufB_hi, bufB_lo, Gh, Gl, dv, m);
    t = tanh4(z + 0.5f*m);
    Ta += 2.f*t;
    WPK(bufA_hi, bufA_lo, t);
    __syncthreads();

    // s4: m = t3@G^T + d ; t4 = tanh(z + m) ; T -> bufB
    STG(bufA_hi, bufA_lo, Gh, Gl, dv, m);
    t = tanh4(z + m);
    Ta += t;
    WPK(bufB_hi, bufB_lo, Ta);
    __syncthreads();

    // s5: z += (T@G^T + 6d)/6 ; wave0: o += (T@Go^T + 6co)/6
    STG(bufB_hi, bufB_lo, Gh, Gl, dv6, m);
    z += (1.f/6.f)*m;
    if (w == 0) {
      f32x4 mo;
      STG(bufB_hi, bufB_lo, goh, gol, cov6, mo);
      o += (1.f/6.f)*mo;
    }
    // no barrier needed: s1 writes bufA (last read before s4's barrier); s2's
    // bufB write is after s1's barrier, by which all s5 bufB reads have drained.
  }
}

extern "C" void kernel_launch(void* const* d_in, const int* in_sizes, int n_in,
                              void* d_out, int out_size, void* d_ws, size_t ws_size,
                              hipStream_t stream) {
  (void)in_sizes; (void)n_in; (void)ws_size; (void)out_size;
  const float* x    = (const float*)d_in[0];
  const float* Win  = (const float*)d_in[1];
  const float* binp = (const float*)d_in[2];
  const float* W1   = (const float*)d_in[3];
  const float* b1   = (const float*)d_in[4];
  const float* W2   = (const float*)d_in[5];
  const float* b2   = (const float*)d_in[6];
  const float* Wout = (const float*)d_in[7];
  const float* bout = (const float*)d_in[8];
  float* ws = (float*)d_ws;

  precomp_kernel<<<69, 256, 0, stream>>>(W1, W2, b2, Wout, ws);
  node_rk4_kernel<<<Bsz / ROWS, 512, 0, stream>>>(x, Win, binp, W1, b1, Wout,
                                                  bout, ws, (float*)d_out);
}

// Round 7
// 110.722 us; speedup vs baseline: 1.7024x; 1.7024x over previous
//
#include <hip/hip_runtime.h>

typedef _Float16 f16x8 __attribute__((ext_vector_type(8)));
typedef _Float16 f16x4 __attribute__((ext_vector_type(4)));
typedef __fp16   h16x2 __attribute__((ext_vector_type(2)));
typedef float    f32x4 __attribute__((ext_vector_type(4)));

#define MFMA16(A, B, C) __builtin_amdgcn_mfma_f32_16x16x32_f16((A), (B), (C), 0, 0, 0)

constexpr int Bsz = 4096, Ssz = 200, INsz = 8, Hsz = 128, OUTsz = 8, Psz = 50;
constexpr int ROWS = 16;   // batch rows per block
// d_ws layout (floats): G[128*128] @0 ; Go[8*128] @16384 ; d[128] @17408 ; co[8] @17536
constexpr int WS_G = 0, WS_GO = 16384, WS_D = 17408, WS_CO = 17536;

// K = 2/ln2 : e^(2x) = exp2(K*x). State kept as zK = K*z.
#define KF   2.8853900817779268f
#define KH   1.4426950408889634f   /* K * 0.5 */
#define K6   0.4808983469629878f   /* K / 6   */
#define KCLAMP 43.2808512266689f   /* K * 15  */

// ---------------- prologue: fold weight products ----------------
// G = W1@W2 (128x128), Go = Wout@W2 (8x128), d = W1@b2 (128), co = Wout@b2 (8)
__global__ void precomp_kernel(const float* __restrict__ W1, const float* __restrict__ W2,
                               const float* __restrict__ b2, const float* __restrict__ Wout,
                               float* __restrict__ ws) {
  int tid = (int)blockIdx.x * 256 + (int)threadIdx.x;
  if (tid < 16384) {                       // G[j][k]
    int j = tid >> 7, k = tid & 127;
    float acc = 0.f;
    #pragma unroll 8
    for (int m = 0; m < 128; ++m) acc = fmaf(W1[j*128 + m], W2[m*128 + k], acc);
    ws[WS_G + tid] = acc;
  } else if (tid < 16384 + 1024) {         // Go[o][k]
    int t = tid - 16384; int o = t >> 7, k = t & 127;
    float acc = 0.f;
    #pragma unroll 8
    for (int m = 0; m < 128; ++m) acc = fmaf(Wout[o*128 + m], W2[m*128 + k], acc);
    ws[WS_GO + t] = acc;
  } else if (tid < 16384 + 1024 + 128) {   // d[j] = sum_m b2[m]*W1[j][m]
    int j = tid - 17408;
    float acc = 0.f;
    for (int m = 0; m < 128; ++m) acc = fmaf(b2[m], W1[j*128 + m], acc);
    ws[WS_D + j] = acc;
  } else if (tid < 16384 + 1024 + 128 + 8) { // co[o] = sum_m b2[m]*Wout[o][m]
    int o = tid - 17536;
    float acc = 0.f;
    for (int m = 0; m < 128; ++m) acc = fmaf(b2[m], Wout[o*128 + m], acc);
    ws[WS_CO + o] = acc;
  }
}

// split fp32 x8 into fp16 hi + fp16 residual (init-time weight frags)
#define SPLIT8(PTR, HI, LO) do { \
    _Pragma("unroll") \
    for (int j_ = 0; j_ < 8; ++j_) { \
      float v_ = (PTR)[j_]; \
      _Float16 h_ = (_Float16)v_; \
      (HI)[j_] = h_; \
      (LO)[j_] = (_Float16)(v_ - (float)h_); \
    } \
  } while (0)

// hi-only split (Go / Wout single-product frags)
#define SPLIT8H(PTR, HI) do { \
    _Pragma("unroll") \
    for (int j_ = 0; j_ < 8; ++j_) (HI)[j_] = (_Float16)(PTR)[j_]; \
  } while (0)

// matmul stage: O = frag(B) @ A^T + bias. 8 ds_read_b128, 12 MFMAs as
// 6 independent chains of depth 2 (short result tail), pairwise adds.
#define STG(BH, BL, AH, AL, BI, O) do { \
    const f16x8 uh0_ = *(const f16x8*)(&(BH)[(0*64 + l)*8]); \
    const f16x8 uh1_ = *(const f16x8*)(&(BH)[(1*64 + l)*8]); \
    const f16x8 uh2_ = *(const f16x8*)(&(BH)[(2*64 + l)*8]); \
    const f16x8 uh3_ = *(const f16x8*)(&(BH)[(3*64 + l)*8]); \
    const f16x8 ul0_ = *(const f16x8*)(&(BL)[(0*64 + l)*8]); \
    const f16x8 ul1_ = *(const f16x8*)(&(BL)[(1*64 + l)*8]); \
    const f16x8 ul2_ = *(const f16x8*)(&(BL)[(2*64 + l)*8]); \
    const f16x8 ul3_ = *(const f16x8*)(&(BL)[(3*64 + l)*8]); \
    f32x4 cA_ = (BI), cB_ = {0.f,0.f,0.f,0.f}; \
    f32x4 eA_ = {0.f,0.f,0.f,0.f}, eB_ = {0.f,0.f,0.f,0.f}; \
    f32x4 fA_ = {0.f,0.f,0.f,0.f}, fB_ = {0.f,0.f,0.f,0.f}; \
    cA_ = MFMA16((AH)[0], uh0_, cA_);  cB_ = MFMA16((AH)[2], uh2_, cB_); \
    eA_ = MFMA16((AL)[0], uh0_, eA_);  eB_ = MFMA16((AL)[2], uh2_, eB_); \
    fA_ = MFMA16((AH)[0], ul0_, fA_);  fB_ = MFMA16((AH)[2], ul2_, fB_); \
    cA_ = MFMA16((AH)[1], uh1_, cA_);  cB_ = MFMA16((AH)[3], uh3_, cB_); \
    eA_ = MFMA16((AL)[1], uh1_, eA_);  eB_ = MFMA16((AL)[3], uh3_, eB_); \
    fA_ = MFMA16((AH)[1], ul1_, fA_);  fB_ = MFMA16((AH)[3], ul3_, fB_); \
    (O) = ((cA_ + cB_) + (eA_ + eB_)) + (fA_ + fB_); \
  } while (0)

// s5/init variant: same as STG, plus wave-0 accumulates the single-product
// output projection (GOH frags) reusing the already-loaded hi frags.
#define STG5(BH, BL, AH, AL, BI, O, GOH, GOBI, MO) do { \
    const f16x8 uh0_ = *(const f16x8*)(&(BH)[(0*64 + l)*8]); \
    const f16x8 uh1_ = *(const f16x8*)(&(BH)[(1*64 + l)*8]); \
    const f16x8 uh2_ = *(const f16x8*)(&(BH)[(2*64 + l)*8]); \
    const f16x8 uh3_ = *(const f16x8*)(&(BH)[(3*64 + l)*8]); \
    const f16x8 ul0_ = *(const f16x8*)(&(BL)[(0*64 + l)*8]); \
    const f16x8 ul1_ = *(const f16x8*)(&(BL)[(1*64 + l)*8]); \
    const f16x8 ul2_ = *(const f16x8*)(&(BL)[(2*64 + l)*8]); \
    const f16x8 ul3_ = *(const f16x8*)(&(BL)[(3*64 + l)*8]); \
    f32x4 cA_ = (BI), cB_ = {0.f,0.f,0.f,0.f}; \
    f32x4 eA_ = {0.f,0.f,0.f,0.f}, eB_ = {0.f,0.f,0.f,0.f}; \
    f32x4 fA_ = {0.f,0.f,0.f,0.f}, fB_ = {0.f,0.f,0.f,0.f}; \
    cA_ = MFMA16((AH)[0], uh0_, cA_);  cB_ = MFMA16((AH)[2], uh2_, cB_); \
    eA_ = MFMA16((AL)[0], uh0_, eA_);  eB_ = MFMA16((AL)[2], uh2_, eB_); \
    fA_ = MFMA16((AH)[0], ul0_, fA_);  fB_ = MFMA16((AH)[2], ul2_, fB_); \
    cA_ = MFMA16((AH)[1], uh1_, cA_);  cB_ = MFMA16((AH)[3], uh3_, cB_); \
    eA_ = MFMA16((AL)[1], uh1_, eA_);  eB_ = MFMA16((AL)[3], uh3_, eB_); \
    fA_ = MFMA16((AH)[1], ul1_, fA_);  fB_ = MFMA16((AH)[3], ul3_, fB_); \
    (O) = ((cA_ + cB_) + (eA_ + eB_)) + (fA_ + fB_); \
    if (w == 0) { \
      f32x4 gA_ = (GOBI), gB_ = {0.f,0.f,0.f,0.f}; \
      gA_ = MFMA16((GOH)[0], uh0_, gA_);  gB_ = MFMA16((GOH)[2], uh2_, gB_); \
      gA_ = MFMA16((GOH)[1], uh1_, gA_);  gB_ = MFMA16((GOH)[3], uh3_, gB_); \
      (MO) = gA_ + gB_; \
    } \
  } while (0)

// write this lane's 4 chans (ch0+4g..+3 of row r) as hi/lo f16x4 via pkrtz
#define WPK(DH, DL, V) do { \
    h16x2 h0_ = __builtin_amdgcn_cvt_pkrtz((V)[0], (V)[1]); \
    h16x2 h1_ = __builtin_amdgcn_cvt_pkrtz((V)[2], (V)[3]); \
    h16x2 l0_ = __builtin_amdgcn_cvt_pkrtz((V)[0] - (float)h0_[0], (V)[1] - (float)h0_[1]); \
    h16x2 l1_ = __builtin_amdgcn_cvt_pkrtz((V)[2] - (float)h1_[0], (V)[3] - (float)h1_[1]); \
    f16x4 wh_, wl_; \
    wh_[0] = (_Float16)h0_[0]; wh_[1] = (_Float16)h0_[1]; \
    wh_[2] = (_Float16)h1_[0]; wh_[3] = (_Float16)h1_[1]; \
    wl_[0] = (_Float16)l0_[0]; wl_[1] = (_Float16)l0_[1]; \
    wl_[2] = (_Float16)l1_[0]; wl_[3] = (_Float16)l1_[1]; \
    *(f16x4*)(&(DH)[wb0]) = wh_; \
    *(f16x4*)(&(DL)[wb0]) = wl_; \
  } while (0)

// tanh from pre-scaled arg zz = K*x: t = 1 - 2/(exp2(zz)+1)
__device__ inline f32x4 tanhK4(f32x4 zz) {
  f32x4 o;
  #pragma unroll
  for (int q = 0; q < 4; ++q) {
    float a = __builtin_amdgcn_fmed3f(zz[q], -KCLAMP, KCLAMP);
    float e = __builtin_amdgcn_exp2f(a);
    float r = __builtin_amdgcn_rcpf(e + 1.f);
    o[q] = fmaf(-2.f, r, 1.f);
  }
  return o;
}

__device__ inline f32x4 fma4(float s, f32x4 a, f32x4 b) {
  f32x4 o;
  #pragma unroll
  for (int q = 0; q < 4; ++q) o[q] = fmaf(s, a[q], b[q]);
  return o;
}

__global__ __launch_bounds__(512, 2) void node_rk4_kernel(
    const float* __restrict__ x,    const float* __restrict__ Win,
    const float* __restrict__ binp, const float* __restrict__ W1,
    const float* __restrict__ b1,   const float* __restrict__ Wout,
    const float* __restrict__ bout, const float* __restrict__ ws,
    float* __restrict__ out)
{
  // packed frag buffers: slot (ks,lane) holds 8 halves = chans [32ks+8*(l>>4)..+8) of row l&15
  __shared__ _Float16 bufA_hi[2048], bufA_lo[2048], bufB_hi[2048], bufB_lo[2048];

  const int tid = (int)threadIdx.x;
  const int w   = tid >> 6;   // wave 0..7, owns channels [16w, 16w+16)
  const int l   = tid & 63;
  const int g   = l >> 4;
  const int r   = l & 15;     // batch row within tile
  const int rowbase = (int)blockIdx.x * ROWS;
  const int ch0 = w * 16;
  // packed write slot for chans ch0+4g+q of row r
  const int wb0 = ((w >> 1)*512 + (2*(w & 1) + (g >> 1))*128 + r*8) + 4*(g & 1);
  const f32x4 zero = {0.f,0.f,0.f,0.f};

  // ---------- persistent weight fragments ----------
  f16x8 Gh[4], Gl[4];              // G rows [ch0+r][*] for this wave's 16 chans
  #pragma unroll
  for (int ks = 0; ks < 4; ++ks)
    SPLIT8(ws + WS_G + (size_t)(ch0 + r)*Hsz + 32*ks + 8*g, Gh[ks], Gl[ks]);

  f16x8 goh[4];                    // Go rows, hi-only (single-product projection)
  #pragma unroll
  for (int ks = 0; ks < 4; ++ks) {
    if (r < OUTsz) SPLIT8H(ws + WS_GO + (size_t)r*Hsz + 32*ks + 8*g, goh[ks]);
    else {
      #pragma unroll
      for (int j = 0; j < 8; ++j) goh[ks][j] = (_Float16)0.f;
    }
  }

  // bias vectors (acc reg q <-> chan ch0+4g+q)
  const f32x4 dv  = *(const f32x4*)(ws + WS_D + ch0 + 4*g);
  const f32x4 dv6 = 6.f * dv;
  f32x4 cov6 = zero, boutv = zero;
  if (w == 0 && g < 2) {
    cov6  = 6.f * *(const f32x4*)(ws + WS_CO + 4*g);
    boutv = *(const f32x4*)(bout + 4*g);
  }

  // ---------- y0 = x[:, S-1, :] @ Win^T + bin (this lane's 4 chans) ----------
  const float* xr = x + ((size_t)(rowbase + r)*Ssz + (Ssz - 1))*INsz;
  const f32x4 xa = *(const f32x4*)xr;
  const f32x4 xb = *(const f32x4*)(xr + 4);
  f32x4 yv;
  {
    const f32x4 binv = *(const f32x4*)(binp + ch0 + 4*g);
    #pragma unroll
    for (int q = 0; q < 4; ++q) {
      const float* wrp = Win + (size_t)(ch0 + 4*g + q)*INsz;
      const f32x4 wa = *(const f32x4*)wrp;
      const f32x4 wb = *(const f32x4*)(wrp + 4);
      float acc = binv[q];
      #pragma unroll
      for (int i = 0; i < 4; ++i) acc += xa[i]*wa[i] + xb[i]*wb[i];
      yv[q] = acc;
    }
  }

  WPK(bufA_hi, bufA_lo, yv);   // stage y0 frags
  __syncthreads();

  // ---------- init: zK = K*(y0@W1^T + b1) ; o = y0@Wout^T (wave 0) ----------
  f32x4 zK, o = zero;
  {
    f16x8 a1h[4], a1l[4];           // transient W1 frags
    #pragma unroll
    for (int ks = 0; ks < 4; ++ks)
      SPLIT8(W1 + (size_t)(ch0 + r)*Hsz + 32*ks + 8*g, a1h[ks], a1l[ks]);
    f16x8 woh[4];                   // transient Wout hi frags (padded)
    #pragma unroll
    for (int ks = 0; ks < 4; ++ks) {
      if (w == 0 && r < OUTsz) SPLIT8H(Wout + (size_t)r*Hsz + 32*ks + 8*g, woh[ks]);
      else {
        #pragma unroll
        for (int j = 0; j < 8; ++j) woh[ks][j] = (_Float16)0.f;
      }
    }
    const f32x4 b1v = *(const f32x4*)(b1 + ch0 + 4*g);
    f32x4 z, mo = zero;
    STG5(bufA_hi, bufA_lo, a1h, a1l, b1v, z, woh, zero, mo);
    zK = KF * z;
    if (w == 0) o = mo;
  }
  __syncthreads();   // bufA readers done before loop's s1 overwrites it

  // ---------- RK4 in zK-space: 4 matmuls + 4 barriers per step ----------
  f32x4 Ta, m, t, mo;
  #pragma unroll 1
  for (int p = 0; p < Psz; ++p) {
    if (w == 0 && g < 2) {   // out_p = o + bout (out chans 4g..4g+3 of row r)
      float* dst = out + ((size_t)(rowbase + r)*Psz + p)*OUTsz + 4*g;
      *(f32x4*)dst = o + boutv;
    }
    if (p == Psz - 1) break;

    // s1: t1 = tanh(z) -> bufA
    t = tanhK4(zK);
    WPK(bufA_hi, bufA_lo, t);
    __syncthreads();
    Ta = t;                                   // sunk into s2's read shadow

    // s2: m1 = t1@G^T + d ; t2 = tanh(z + 0.5 m1) -> bufB
    STG(bufA_hi, bufA_lo, Gh, Gl, dv, m);
    t = tanhK4(fma4(KH, m, zK));
    WPK(bufB_hi, bufB_lo, t);
    __syncthreads();
    Ta = Ta + 2.f*t;                          // sunk

    // s3: m2 = t2@G^T + d ; t3 = tanh(z + 0.5 m2) -> bufA
    STG(bufB_hi, bufB_lo, Gh, Gl, dv, m);
    t = tanhK4(fma4(KH, m, zK));
    WPK(bufA_hi, bufA_lo, t);
    __syncthreads();
    Ta = Ta + 2.f*t;                          // sunk

    // s4: m3 = t3@G^T + d ; t4 = tanh(z + m3) ; T -> bufB
    STG(bufA_hi, bufA_lo, Gh, Gl, dv, m);
    t = tanhK4(fma4(KF, m, zK));
    Ta = Ta + t;
    WPK(bufB_hi, bufB_lo, Ta);
    __syncthreads();

    // s5: zK += (K/6)(T@G^T + 6d) ; wave0: o += (T@Go^T + 6co)/6 (frags reused)
    STG5(bufB_hi, bufB_lo, Gh, Gl, dv6, m, goh, cov6, mo);
    zK = fma4(K6, m, zK);
    if (w == 0) o = o + (1.f/6.f)*mo;
    // no barrier: s1 writes bufA (last read before s4's barrier); s2's bufB
    // write is after s1's barrier, by which all s5 bufB reads have drained.
  }
}

extern "C" void kernel_launch(void* const* d_in, const int* in_sizes, int n_in,
                              void* d_out, int out_size, void* d_ws, size_t ws_size,
                              hipStream_t stream) {
  (void)in_sizes; (void)n_in; (void)ws_size; (void)out_size;
  const float* x    = (const float*)d_in[0];
  const float* Win  = (const float*)d_in[1];
  const float* binp = (const float*)d_in[2];
  const float* W1   = (const float*)d_in[3];
  const float* b1   = (const float*)d_in[4];
  const float* W2   = (const float*)d_in[5];
  const float* b2   = (const float*)d_in[6];
  const float* Wout = (const float*)d_in[7];
  const float* bout = (const float*)d_in[8];
  float* ws = (float*)d_ws;

  precomp_kernel<<<69, 256, 0, stream>>>(W1, W2, b2, Wout, ws);
  node_rk4_kernel<<<Bsz / ROWS, 512, 0, stream>>>(x, Win, binp, W1, b1, Wout,
                                                  bout, ws, (float*)d_out);
}

// Round 8
// 109.999 us; speedup vs baseline: 1.7136x; 1.0066x over previous
//
#include <hip/hip_runtime.h>

typedef _Float16 f16x8 __attribute__((ext_vector_type(8)));
typedef _Float16 f16x4 __attribute__((ext_vector_type(4)));
typedef __fp16   h16x2 __attribute__((ext_vector_type(2)));
typedef float    f32x4 __attribute__((ext_vector_type(4)));

#define MFMA16(A, B, C) __builtin_amdgcn_mfma_f32_16x16x32_f16((A), (B), (C), 0, 0, 0)

constexpr int Bsz = 4096, Ssz = 200, INsz = 8, Hsz = 128, OUTsz = 8, Psz = 50;
constexpr int ROWS = 16;   // batch rows per block
// d_ws layout (floats): G[128*128] @0 ; Go[8*128] @16384 ; d[128] @17408 ; co[8] @17536
constexpr int WS_G = 0, WS_GO = 16384, WS_D = 17408, WS_CO = 17536;

// ---------------- prologue: fold weight products ----------------
// G = W1@W2 (128x128), Go = Wout@W2 (8x128), d = W1@b2 (128), co = Wout@b2 (8)
__global__ void precomp_kernel(const float* __restrict__ W1, const float* __restrict__ W2,
                               const float* __restrict__ b2, const float* __restrict__ Wout,
                               float* __restrict__ ws) {
  int tid = (int)blockIdx.x * 256 + (int)threadIdx.x;
  if (tid < 16384) {                       // G[j][k]
    int j = tid >> 7, k = tid & 127;
    float acc = 0.f;
    #pragma unroll 8
    for (int m = 0; m < 128; ++m) acc = fmaf(W1[j*128 + m], W2[m*128 + k], acc);
    ws[WS_G + tid] = acc;
  } else if (tid < 16384 + 1024) {         // Go[o][k]
    int t = tid - 16384; int o = t >> 7, k = t & 127;
    float acc = 0.f;
    #pragma unroll 8
    for (int m = 0; m < 128; ++m) acc = fmaf(Wout[o*128 + m], W2[m*128 + k], acc);
    ws[WS_GO + t] = acc;
  } else if (tid < 16384 + 1024 + 128) {   // d[j] = sum_m b2[m]*W1[j][m]
    int j = tid - 17408;
    float acc = 0.f;
    for (int m = 0; m < 128; ++m) acc = fmaf(b2[m], W1[j*128 + m], acc);
    ws[WS_D + j] = acc;
  } else if (tid < 16384 + 1024 + 128 + 8) { // co[o] = sum_m b2[m]*Wout[o][m]
    int o = tid - 17536;
    float acc = 0.f;
    for (int m = 0; m < 128; ++m) acc = fmaf(b2[m], Wout[o*128 + m], acc);
    ws[WS_CO + o] = acc;
  }
}

// split fp32 x8 into fp16 hi + fp16 residual (register-resident weight frags)
#define SPLIT8(PTR, HI, LO) do { \
    _Pragma("unroll") \
    for (int j_ = 0; j_ < 8; ++j_) { \
      float v_ = (PTR)[j_]; \
      _Float16 h_ = (_Float16)v_; \
      (HI)[j_] = h_; \
      (LO)[j_] = (_Float16)(v_ - (float)h_); \
    } \
  } while (0)

// hi-only split (Go / Wout single-product frags)
#define SPLIT8H(PTR, HI) do { \
    _Pragma("unroll") \
    for (int j_ = 0; j_ < 8; ++j_) (HI)[j_] = (_Float16)(PTR)[j_]; \
  } while (0)

// matmul stage: O = frag(B) @ A^T + bias ; packed conflict-free LDS reads;
// 3-product hi/lo split (uh*Wh + uh*Wl + ul*Wh), 3 chains of depth 4. (R3 form)
#define STG(BH, BL, AH, AL, BI, O) do { \
    f32x4 c_ = (BI); \
    f32x4 e_ = {0.f,0.f,0.f,0.f}, f_ = {0.f,0.f,0.f,0.f}; \
    _Pragma("unroll") \
    for (int ks_ = 0; ks_ < 4; ++ks_) { \
      const f16x8 uh_ = *(const f16x8*)(&(BH)[(ks_*64 + l)*8]); \
      const f16x8 ul_ = *(const f16x8*)(&(BL)[(ks_*64 + l)*8]); \
      c_ = MFMA16((AH)[ks_], uh_, c_); \
      e_ = MFMA16((AL)[ks_], uh_, e_); \
      f_ = MFMA16((AH)[ks_], ul_, f_); \
    } \
    (O) = c_ + e_ + f_; \
  } while (0)

// s5/init variant: STG plus wave-0 accumulates the single-product output
// projection (GOH frags) reusing the already-loaded hi frags (no extra reads).
#define STG5(BH, BL, AH, AL, BI, O, GOH, GOBI, MO) do { \
    f32x4 c_ = (BI); \
    f32x4 e_ = {0.f,0.f,0.f,0.f}, f_ = {0.f,0.f,0.f,0.f}; \
    f32x4 g_ = (GOBI); \
    _Pragma("unroll") \
    for (int ks_ = 0; ks_ < 4; ++ks_) { \
      const f16x8 uh_ = *(const f16x8*)(&(BH)[(ks_*64 + l)*8]); \
      const f16x8 ul_ = *(const f16x8*)(&(BL)[(ks_*64 + l)*8]); \
      c_ = MFMA16((AH)[ks_], uh_, c_); \
      e_ = MFMA16((AL)[ks_], uh_, e_); \
      f_ = MFMA16((AH)[ks_], ul_, f_); \
      if (w == 0) g_ = MFMA16((GOH)[ks_], uh_, g_); \
    } \
    (O) = c_ + e_ + f_; \
    if (w == 0) (MO) = g_; \
  } while (0)

// write this lane's 4 chans (ch0+4g..+3 of row r) as hi/lo f16x4 via pkrtz
#define WPK(DH, DL, V) do { \
    h16x2 h0_ = __builtin_amdgcn_cvt_pkrtz((V)[0], (V)[1]); \
    h16x2 h1_ = __builtin_amdgcn_cvt_pkrtz((V)[2], (V)[3]); \
    h16x2 l0_ = __builtin_amdgcn_cvt_pkrtz((V)[0] - (float)h0_[0], (V)[1] - (float)h0_[1]); \
    h16x2 l1_ = __builtin_amdgcn_cvt_pkrtz((V)[2] - (float)h1_[0], (V)[3] - (float)h1_[1]); \
    f16x4 wh_, wl_; \
    wh_[0] = (_Float16)h0_[0]; wh_[1] = (_Float16)h0_[1]; \
    wh_[2] = (_Float16)h1_[0]; wh_[3] = (_Float16)h1_[1]; \
    wl_[0] = (_Float16)l0_[0]; wl_[1] = (_Float16)l0_[1]; \
    wl_[2] = (_Float16)l1_[0]; wl_[3] = (_Float16)l1_[1]; \
    *(f16x4*)(&(DH)[wb0]) = wh_; \
    *(f16x4*)(&(DL)[wb0]) = wl_; \
  } while (0)

__device__ inline f32x4 tanh4(f32x4 z) {
  f32x4 o;
  #pragma unroll
  for (int q = 0; q < 4; ++q) {
    float zz = fminf(fmaxf(z[q], -15.f), 15.f);
    float e  = __builtin_amdgcn_exp2f(2.8853900817779268f * zz); // e^(2x)
    o[q] = (e - 1.f) * __builtin_amdgcn_rcpf(e + 1.f);
  }
  return o;
}

__global__ __launch_bounds__(512, 2) void node_rk4_kernel(
    const float* __restrict__ x,    const float* __restrict__ Win,
    const float* __restrict__ binp, const float* __restrict__ W1,
    const float* __restrict__ b1,   const float* __restrict__ Wout,
    const float* __restrict__ bout, const float* __restrict__ ws,
    float* __restrict__ out)
{
  // packed frag buffers: slot (ks,lane) holds 8 halves = chans [32ks+8*(l>>4)..+8) of row l&15
  __shared__ _Float16 bufA_hi[2048], bufA_lo[2048], bufB_hi[2048], bufB_lo[2048];

  const int tid = (int)threadIdx.x;
  const int w   = tid >> 6;   // wave 0..7, owns channels [16w, 16w+16)
  const int l   = tid & 63;
  const int g   = l >> 4;
  const int r   = l & 15;     // batch row within tile
  const int rowbase = (int)blockIdx.x * ROWS;
  const int ch0 = w * 16;
  // packed write slot for chans ch0+4g+q of row r
  const int wb0 = ((w >> 1)*512 + (2*(w & 1) + (g >> 1))*128 + r*8) + 4*(g & 1);
  const f32x4 zero = {0.f,0.f,0.f,0.f};

  // ---------- persistent weight fragments ----------
  f16x8 Gh[4], Gl[4];              // G rows [ch0+r][*] for this wave's 16 chans
  #pragma unroll
  for (int ks = 0; ks < 4; ++ks)
    SPLIT8(ws + WS_G + (size_t)(ch0 + r)*Hsz + 32*ks + 8*g, Gh[ks], Gl[ks]);

  f16x8 goh[4];                    // Go rows, hi-only (single-product projection)
  #pragma unroll
  for (int ks = 0; ks < 4; ++ks) {
    if (r < OUTsz) SPLIT8H(ws + WS_GO + (size_t)r*Hsz + 32*ks + 8*g, goh[ks]);
    else {
      #pragma unroll
      for (int j = 0; j < 8; ++j) goh[ks][j] = (_Float16)0.f;
    }
  }

  // bias vectors (acc reg q <-> chan ch0+4g+q)
  const f32x4 dv  = *(const f32x4*)(ws + WS_D + ch0 + 4*g);
  const f32x4 dv6 = 6.f * dv;
  f32x4 cov6 = zero, boutv = zero;
  if (w == 0 && g < 2) {
    cov6  = 6.f * *(const f32x4*)(ws + WS_CO + 4*g);
    boutv = *(const f32x4*)(bout + 4*g);
  }

  // ---------- y0 = x[:, S-1, :] @ Win^T + bin (this lane's 4 chans) ----------
  const float* xr = x + ((size_t)(rowbase + r)*Ssz + (Ssz - 1))*INsz;
  const f32x4 xa = *(const f32x4*)xr;
  const f32x4 xb = *(const f32x4*)(xr + 4);
  f32x4 yv;
  {
    const f32x4 binv = *(const f32x4*)(binp + ch0 + 4*g);
    #pragma unroll
    for (int q = 0; q < 4; ++q) {
      const float* wrp = Win + (size_t)(ch0 + 4*g + q)*INsz;
      const f32x4 wa = *(const f32x4*)wrp;
      const f32x4 wb = *(const f32x4*)(wrp + 4);
      float acc = binv[q];
      #pragma unroll
      for (int i = 0; i < 4; ++i) acc += xa[i]*wa[i] + xb[i]*wb[i];
      yv[q] = acc;
    }
  }

  WPK(bufA_hi, bufA_lo, yv);   // stage y0 frags
  __syncthreads();

  // ---------- init: z = y0@W1^T + b1 (all waves), o = y0@Wout^T (wave 0, fused) ----------
  f32x4 z, o = zero;
  {
    f16x8 a1h[4], a1l[4];           // transient W1 frags
    #pragma unroll
    for (int ks = 0; ks < 4; ++ks)
      SPLIT8(W1 + (size_t)(ch0 + r)*Hsz + 32*ks + 8*g, a1h[ks], a1l[ks]);
    f16x8 woh[4];                   // transient Wout hi frags (padded)
    #pragma unroll
    for (int ks = 0; ks < 4; ++ks) {
      if (w == 0 && r < OUTsz) SPLIT8H(Wout + (size_t)r*Hsz + 32*ks + 8*g, woh[ks]);
      else {
        #pragma unroll
        for (int j = 0; j < 8; ++j) woh[ks][j] = (_Float16)0.f;
      }
    }
    const f32x4 b1v = *(const f32x4*)(b1 + ch0 + 4*g);
    f32x4 mo = zero;
    STG5(bufA_hi, bufA_lo, a1h, a1l, b1v, z, woh, zero, mo);
    if (w == 0) o = mo;
  }
  __syncthreads();   // bufA readers done before loop's s1 overwrites it

  // ---------- RK4 in z-space: 4 matmuls + 4 barriers per step ----------
  f32x4 Ta, m, t, mo;
  #pragma unroll 1
  for (int p = 0; p < Psz; ++p) {
    if (w == 0 && g < 2) {   // out_p = o + bout (out chans 4g..4g+3 of row r)
      float* dst = out + ((size_t)(rowbase + r)*Psz + p)*OUTsz + 4*g;
      *(f32x4*)dst = o + boutv;
    }
    if (p == Psz - 1) break;

    // s1: t1 = tanh(z) ; Ta = t1 ; -> bufA
    t = tanh4(z);
    Ta = t;
    WPK(bufA_hi, bufA_lo, t);
    __syncthreads();

    // s2: m1 = t1@G^T + d ; t2 = tanh(z + 0.5 m1) -> bufB
    STG(bufA_hi, bufA_lo, Gh, Gl, dv, m);
    t = tanh4(z + 0.5f*m);
    Ta += 2.f*t;
    WPK(bufB_hi, bufB_lo, t);
    __syncthreads();

    // s3: m2 = t2@G^T + d ; t3 = tanh(z + 0.5 m2) -> bufA
    STG(bufB_hi, bufB_lo, Gh, Gl, dv, m);
    t = tanh4(z + 0.5f*m);
    Ta += 2.f*t;
    WPK(bufA_hi, bufA_lo, t);
    __syncthreads();

    // s4: m3 = t3@G^T + d ; t4 = tanh(z + m3) ; T -> bufB
    STG(bufA_hi, bufA_lo, Gh, Gl, dv, m);
    t = tanh4(z + m);
    Ta += t;
    WPK(bufB_hi, bufB_lo, Ta);
    __syncthreads();

    // s5: z += (T@G^T + 6d)/6 ; wave0: o += (T@Go^T + 6co)/6 (frags reused, fused)
    STG5(bufB_hi, bufB_lo, Gh, Gl, dv6, m, goh, cov6, mo);
    z += (1.f/6.f)*m;
    if (w == 0) o += (1.f/6.f)*mo;
    // no barrier: s1 writes bufA (last read before s4's barrier); s2's bufB
    // write is after s1's barrier, by which all s5 bufB reads have drained.
  }
}

extern "C" void kernel_launch(void* const* d_in, const int* in_sizes, int n_in,
                              void* d_out, int out_size, void* d_ws, size_t ws_size,
                              hipStream_t stream) {
  (void)in_sizes; (void)n_in; (void)ws_size; (void)out_size;
  const float* x    = (const float*)d_in[0];
  const float* Win  = (const float*)d_in[1];
  const float* binp = (const float*)d_in[2];
  const float* W1   = (const float*)d_in[3];
  const float* b1   = (const float*)d_in[4];
  const float* W2   = (const float*)d_in[5];
  const float* b2   = (const float*)d_in[6];
  const float* Wout = (const float*)d_in[7];
  const float* bout = (const float*)d_in[8];
  float* ws = (float*)d_ws;

  precomp_kernel<<<69, 256, 0, stream>>>(W1, W2, b2, Wout, ws);
  node_rk4_kernel<<<Bsz / ROWS, 512, 0, stream>>>(x, Win, binp, W1, b1, Wout,
                                                  bout, ws, (float*)d_out);
}

// Round 9
// 106.079 us; speedup vs baseline: 1.7769x; 1.0370x over previous
//
#include <hip/hip_runtime.h>

typedef _Float16 f16x8 __attribute__((ext_vector_type(8)));
typedef _Float16 f16x4 __attribute__((ext_vector_type(4)));
typedef float    f32x4 __attribute__((ext_vector_type(4)));

#define MFMA16(A, B, C) __builtin_amdgcn_mfma_f32_16x16x32_f16((A), (B), (C), 0, 0, 0)

constexpr int Bsz = 4096, Ssz = 200, INsz = 8, Hsz = 128, OUTsz = 8, Psz = 50;
constexpr int ROWS = 16;   // batch rows per block
// d_ws layout (floats): G[128*128] @0 ; Go[8*128] @16384 ; d[128] @17408 ; co[8] @17536
constexpr int WS_G = 0, WS_GO = 16384, WS_D = 17408, WS_CO = 17536;

// ---------------- prologue: fold weight products ----------------
// G = W1@W2 (128x128), Go = Wout@W2 (8x128), d = W1@b2 (128), co = Wout@b2 (8)
__global__ void precomp_kernel(const float* __restrict__ W1, const float* __restrict__ W2,
                               const float* __restrict__ b2, const float* __restrict__ Wout,
                               float* __restrict__ ws) {
  int tid = (int)blockIdx.x * 256 + (int)threadIdx.x;
  if (tid < 16384) {                       // G[j][k]
    int j = tid >> 7, k = tid & 127;
    float acc = 0.f;
    #pragma unroll 8
    for (int m = 0; m < 128; ++m) acc = fmaf(W1[j*128 + m], W2[m*128 + k], acc);
    ws[WS_G + tid] = acc;
  } else if (tid < 16384 + 1024) {         // Go[o][k]
    int t = tid - 16384; int o = t >> 7, k = t & 127;
    float acc = 0.f;
    #pragma unroll 8
    for (int m = 0; m < 128; ++m) acc = fmaf(Wout[o*128 + m], W2[m*128 + k], acc);
    ws[WS_GO + t] = acc;
  } else if (tid < 16384 + 1024 + 128) {   // d[j] = sum_m b2[m]*W1[j][m]
    int j = tid - 17408;
    float acc = 0.f;
    for (int m = 0; m < 128; ++m) acc = fmaf(b2[m], W1[j*128 + m], acc);
    ws[WS_D + j] = acc;
  } else if (tid < 16384 + 1024 + 128 + 8) { // co[o] = sum_m b2[m]*Wout[o][m]
    int o = tid - 17536;
    float acc = 0.f;
    for (int m = 0; m < 128; ++m) acc = fmaf(b2[m], Wout[o*128 + m], acc);
    ws[WS_CO + o] = acc;
  }
}

// split fp32 x8 into fp16 hi + fp16 residual (register-resident weight frags)
#define SPLIT8(PTR, HI, LO) do { \
    const f32x4 va_ = *(const f32x4*)(PTR); \
    const f32x4 vb_ = *(const f32x4*)((PTR) + 4); \
    _Pragma("unroll") \
    for (int j_ = 0; j_ < 4; ++j_) { \
      _Float16 h0_ = (_Float16)va_[j_]; \
      (HI)[j_]     = h0_; \
      (LO)[j_]     = (_Float16)(va_[j_] - (float)h0_); \
      _Float16 h1_ = (_Float16)vb_[j_]; \
      (HI)[j_ + 4] = h1_; \
      (LO)[j_ + 4] = (_Float16)(vb_[j_] - (float)h1_); \
    } \
  } while (0)

// single-tile matmul stage: O = frag(B) @ A^T + bias ; packed conflict-free LDS
// reads; 3-product hi/lo split (uh*Wh + uh*Wl + ul*Wh), 3 chains of depth 4.
#define STG(BH, BL, AH, AL, BI, O) do { \
    f32x4 c_ = (BI); \
    f32x4 e_ = {0.f,0.f,0.f,0.f}, f_ = {0.f,0.f,0.f,0.f}; \
    _Pragma("unroll") \
    for (int ks_ = 0; ks_ < 4; ++ks_) { \
      const f16x8 uh_ = *(const f16x8*)(&(BH)[(ks_*64 + l)*8]); \
      const f16x8 ul_ = *(const f16x8*)(&(BL)[(ks_*64 + l)*8]); \
      c_ = MFMA16((AH)[ks_], uh_, c_); \
      e_ = MFMA16((AL)[ks_], uh_, e_); \
      f_ = MFMA16((AH)[ks_], ul_, f_); \
    } \
    (O) = c_ + e_ + f_; \
  } while (0)

// write this lane's 4 channels (chans ch0+4g..+3 of batch row r) into the
// packed hi/lo frag arrays at precomputed slot wb0 (one ds_write_b64 each)
#define WPK(DH, DL, V) do { \
    f16x4 wh_, wl_; \
    _Pragma("unroll") \
    for (int q_ = 0; q_ < 4; ++q_) { \
      _Float16 hh_ = (_Float16)(V)[q_]; \
      wh_[q_] = hh_; wl_[q_] = (_Float16)((V)[q_] - (float)hh_); \
    } \
    *(f16x4*)(&(DH)[wb0]) = wh_; \
    *(f16x4*)(&(DL)[wb0]) = wl_; \
  } while (0)

__device__ inline f32x4 tanh4(f32x4 z) {
  f32x4 o;
  #pragma unroll
  for (int q = 0; q < 4; ++q) {
    float zz = fminf(fmaxf(z[q], -15.f), 15.f);
    float e  = __builtin_amdgcn_exp2f(2.8853900817779268f * zz); // e^(2x)
    o[q] = (e - 1.f) * __builtin_amdgcn_rcpf(e + 1.f);
  }
  return o;
}

__global__ __launch_bounds__(512, 2) void node_rk4_kernel(
    const float* __restrict__ x,    const float* __restrict__ Win,
    const float* __restrict__ binp, const float* __restrict__ W1,
    const float* __restrict__ b1,   const float* __restrict__ Wout,
    const float* __restrict__ bout, const float* __restrict__ ws,
    float* __restrict__ out)
{
  // packed frag buffers: slot (ks,lane) holds 8 halves = chans [32ks+8*(l>>4)..+8) of row l&15
  __shared__ _Float16 bufA_hi[2048], bufA_lo[2048], bufB_hi[2048], bufB_lo[2048];

  const int tid = (int)threadIdx.x;
  const int w   = tid >> 6;   // wave 0..7, owns channels [16w, 16w+16)
  const int l   = tid & 63;
  const int g   = l >> 4;
  const int r   = l & 15;     // batch row within tile
  const int rowbase = (int)blockIdx.x * ROWS;
  const int ch0 = w * 16;
  // packed write slot for chans ch0+4g+q of row r
  const int wb0 = ((w >> 1)*512 + (2*(w & 1) + (g >> 1))*128 + r*8) + 4*(g & 1);

  // ---------- persistent weight fragments ----------
  f16x8 Gh[4], Gl[4];              // G rows [ch0+r][*] for this wave's 16 chans
  #pragma unroll
  for (int ks = 0; ks < 4; ++ks)
    SPLIT8(ws + WS_G + (size_t)(ch0 + r)*Hsz + 32*ks + 8*g, Gh[ks], Gl[ks]);

  f16x8 goh[4], gol[4];            // Go rows (8 real, padded to 16) — used by wave 0
  #pragma unroll
  for (int ks = 0; ks < 4; ++ks) {
    if (r < OUTsz) SPLIT8(ws + WS_GO + (size_t)r*Hsz + 32*ks + 8*g, goh[ks], gol[ks]);
    else {
      #pragma unroll
      for (int j = 0; j < 8; ++j) { goh[ks][j] = (_Float16)0.f; gol[ks][j] = (_Float16)0.f; }
    }
  }

  // bias vectors (acc reg q <-> chan ch0+4g+q)
  const f32x4 dv  = *(const f32x4*)(ws + WS_D + ch0 + 4*g);
  const f32x4 dv6 = 6.f * dv;
  f32x4 cov6, boutv;
  if (g < 2) { cov6 = 6.f * *(const f32x4*)(ws + WS_CO + 4*g);
               boutv = *(const f32x4*)(bout + 4*g); }
  else { cov6 = f32x4{0.f,0.f,0.f,0.f}; boutv = f32x4{0.f,0.f,0.f,0.f}; }

  // ---------- y0 = x[:, S-1, :] @ Win^T + bin (this lane's 4 chans) ----------
  const float* xr = x + ((size_t)(rowbase + r)*Ssz + (Ssz - 1))*INsz;
  const f32x4 xa = *(const f32x4*)xr;
  const f32x4 xb = *(const f32x4*)(xr + 4);
  f32x4 yv;
  {
    const f32x4 binv = *(const f32x4*)(binp + ch0 + 4*g);
    #pragma unroll
    for (int q = 0; q < 4; ++q) {
      const float* wrp = Win + (size_t)(ch0 + 4*g + q)*INsz;
      const f32x4 wa = *(const f32x4*)wrp;
      const f32x4 wb = *(const f32x4*)(wrp + 4);
      float acc = binv[q];
      #pragma unroll
      for (int i = 0; i < 4; ++i) acc += xa[i]*wa[i] + xb[i]*wb[i];
      yv[q] = acc;
    }
  }

  WPK(bufA_hi, bufA_lo, yv);   // stage y0 frags
  __syncthreads();

  // ---------- init: z = y0@W1^T + b1 (all waves), o = y0@Wout^T (wave 0) ----------
  f32x4 z, o;
  {
    f16x8 a1h[4], a1l[4];           // transient W1 frags
    #pragma unroll
    for (int ks = 0; ks < 4; ++ks)
      SPLIT8(W1 + (size_t)(ch0 + r)*Hsz + 32*ks + 8*g, a1h[ks], a1l[ks]);
    const f32x4 b1v = *(const f32x4*)(b1 + ch0 + 4*g);
    STG(bufA_hi, bufA_lo, a1h, a1l, b1v, z);

    if (w == 0) {
      f16x8 woh[4], wol[4];         // transient Wout frags (padded)
      #pragma unroll
      for (int ks = 0; ks < 4; ++ks) {
        if (r < OUTsz) SPLIT8(Wout + (size_t)r*Hsz + 32*ks + 8*g, woh[ks], wol[ks]);
        else {
          #pragma unroll
          for (int j = 0; j < 8; ++j) { woh[ks][j] = (_Float16)0.f; wol[ks][j] = (_Float16)0.f; }
        }
      }
      const f32x4 zero = {0.f,0.f,0.f,0.f};
      STG(bufA_hi, bufA_lo, woh, wol, zero, o);
    } else {
      o = f32x4{0.f,0.f,0.f,0.f};
    }
  }
  __syncthreads();   // bufA readers done before loop's s1 overwrites it

  // ---------- RK4 in z-space: 4 matmuls + 4 barriers per step ----------
  f32x4 Ta, m, t;
  #pragma unroll 1
  for (int p = 0; p < Psz; ++p) {
    if (w == 0 && g < 2) {   // out_p = o + bout (lane covers out chans 4g..4g+3 of row r)
      float* dst = out + ((size_t)(rowbase + r)*Psz + p)*OUTsz + 4*g;
      *(f32x4*)dst = o + boutv;
    }
    if (p == Psz - 1) break;

    // s1: t1 = tanh(z) ; Ta = t1 ; -> bufA
    t = tanh4(z);
    Ta = t;
    WPK(bufA_hi, bufA_lo, t);
    __syncthreads();

    // s2: m = t1@G^T + d ; t2 = tanh(z + 0.5m) -> bufB
    STG(bufA_hi, bufA_lo, Gh, Gl, dv, m);
    t = tanh4(z + 0.5f*m);
    Ta += 2.f*t;
    WPK(bufB_hi, bufB_lo, t);
    __syncthreads();

    // s3: m = t2@G^T + d ; t3 = tanh(z + 0.5m) -> bufA
    STG(bufB_hi, bufB_lo, Gh, Gl, dv, m);
    t = tanh4(z + 0.5f*m);
    Ta += 2.f*t;
    WPK(bufA_hi, bufA_lo, t);
    __syncthreads();

    // s4: m = t3@G^T + d ; t4 = tanh(z + m) ; T -> bufB
    STG(bufA_hi, bufA_lo, Gh, Gl, dv, m);
    t = tanh4(z + m);
    Ta += t;
    WPK(bufB_hi, bufB_lo, Ta);
    __syncthreads();

    // s5: z += (T@G^T + 6d)/6 ; wave0: o += (T@Go^T + 6co)/6
    STG(bufB_hi, bufB_lo, Gh, Gl, dv6, m);
    z += (1.f/6.f)*m;
    if (w == 0) {
      f32x4 mo;
      STG(bufB_hi, bufB_lo, goh, gol, cov6, mo);
      o += (1.f/6.f)*mo;
    }
    // no barrier needed: s1 writes bufA (last read before s4's barrier); s2's
    // bufB write is after s1's barrier, by which all s5 bufB reads have drained.
  }
}

extern "C" void kernel_launch(void* const* d_in, const int* in_sizes, int n_in,
                              void* d_out, int out_size, void* d_ws, size_t ws_size,
                              hipStream_t stream) {
  (void)in_sizes; (void)n_in; (void)ws_size; (void)out_size;
  const float* x    = (const float*)d_in[0];
  const float* Win  = (const float*)d_in[1];
  const float* binp = (const float*)d_in[2];
  const float* W1   = (const float*)d_in[3];
  const float* b1   = (const float*)d_in[4];
  const float* W2   = (const float*)d_in[5];
  const float* b2   = (const float*)d_in[6];
  const float* Wout = (const float*)d_in[7];
  const float* bout = (const float*)d_in[8];
  float* ws = (float*)d_ws;

  precomp_kernel<<<69, 256, 0, stream>>>(W1, W2, b2, Wout, ws);
  node_rk4_kernel<<<Bsz / ROWS, 512, 0, stream>>>(x, Win, binp, W1, b1, Wout,
                                                  bout, ws, (float*)d_out);
}